// Round 11
// baseline (253.349 us; speedup 1.0000x reference)
//
#include <hip/hip_runtime.h>
#include <hip/hip_cooperative_groups.h>
#include <hip/hip_fp16.h>
#include <math.h>

namespace cg = cooperative_groups;

#define DIM   512
#define NBLK  256
#define NTHR  1024
#define NROW  2              // rows per block; 256 blocks * 2 = 512

typedef _Float16 h2 __attribute__((ext_vector_type(2)));

#if __has_builtin(__builtin_amdgcn_fdot2)
__device__ __forceinline__ float dot2f(unsigned a, unsigned b, float c){
  return __builtin_amdgcn_fdot2(__builtin_bit_cast(h2, a), __builtin_bit_cast(h2, b), c, false);
}
#else
__device__ __forceinline__ float dot2f(unsigned au, unsigned bu, float c){
  h2 a = __builtin_bit_cast(h2, au), b = __builtin_bit_cast(h2, bu);
  return fmaf((float)a[0], (float)b[0], fmaf((float)a[1], (float)b[1], c));
}
#endif

// ---- RKF56 coefficients ----
constexpr float cA21 = 0.25f;
constexpr float cA31 = (float)(3.0/32.0),     cA32 = (float)(9.0/32.0);
constexpr float cA41 = (float)(1932.0/2197.0),cA42 = (float)(-7200.0/2197.0), cA43 = (float)(7296.0/2197.0);
constexpr float cA51 = (float)(439.0/216.0),  cA52 = -8.0f,                   cA53 = (float)(3680.0/513.0), cA54 = (float)(-845.0/4104.0);
constexpr float cA61 = (float)(-8.0/27.0),    cA62 = 2.0f,                    cA63 = (float)(-3544.0/2565.0), cA64 = (float)(1859.0/4104.0), cA65 = (float)(-11.0/40.0);
constexpr float cB1 = (float)(16.0/135.0), cB3 = (float)(6656.0/12825.0), cB4 = (float)(28561.0/56430.0), cB5 = (float)(-9.0/50.0), cB6 = (float)(2.0/55.0);
constexpr float cC1 = (float)(25.0/216.0), cC3 = (float)(1408.0/2565.0),  cC4 = (float)(2197.0/4104.0),  cC5 = -0.2f;

constexpr float TOLf = 0.01f, MIN_DTf = 0.1f, DT0f = 0.1f, MAXTf = 50.0f, VELTOLf = 0.05f;
constexpr float INVD = 1.0f/512.0f;

__device__ __forceinline__ unsigned packh(float a, float b){
  unsigned short lo = __half_as_ushort(__float2half(a));   // RNE
  unsigned short hi = __half_as_ushort(__float2half(b));
  return (unsigned)lo | ((unsigned)hi << 16);
}

__global__ void __launch_bounds__(NTHR, 1)
hop_kernel(const float* __restrict__ x0, const float* __restrict__ W,
           const float* __restrict__ bvec, float* __restrict__ out,
           unsigned char* __restrict__ ws)
{
  cg::grid_group grid = cg::this_grid();

  unsigned*           bar  = (unsigned*)ws;                    // 64 slots
  unsigned*           errs = (unsigned*)(ws + 384);            // errs[32]
  unsigned long long* vels = (unsigned long long*)(ws + 512);  // vels[32]
  unsigned*           Wq   = (unsigned*)(ws + 4096);           // [kp/4][c][kp&3] f16x2, 512 KB
  unsigned*           WTq  = Wq + 131072;                      // transposed, 512 KB

  const int tid  = threadIdx.x;
  const int b    = blockIdx.x;
  const int wid  = tid >> 6;           // wave 0..15
  const int lane = tid & 63;

  // matmul coords: k-slice x column-group (cols cg+128j, coalesced)
  const int ks  = tid >> 7;            // 0..7  (kp range [ks*32, ks*32+32))
  const int cgi = tid & 127;           // 0..127
  // pointwise coords: one row, ONE column
  const int pr   = tid >> 9;           // 0..1  (== wid>>3)
  const int pcl  = tid & 511;          // col 0..511
  const int grow = b*NROW + pr;        // global batch row

  __shared__ __align__(16) unsigned short ylds[NROW][DIM];   // f16 y, 2 KB
  __shared__ __align__(16) unsigned short slds[NROW][DIM];   // f16 sech2, 2 KB
  __shared__ __align__(16) float sPart[8][NROW][DIM];        // k-slice partials, 32 KB
  __shared__ float red[16];
  __shared__ float bcast[4];

  // ---- one-time: W -> interleaved packed f16 (normal + transposed) ----
  {
    int e = b*NTHR + tid;               // [0, 262144): half pack Wq, half WTq
    int ei = e & 131071;
    int kpq = ei >> 11, rem = ei & 2047;
    int c = rem >> 2, k3 = rem & 3;
    int kp = kpq*4 + k3;
    if (e < 131072){
      Wq[ei] = packh(W[(size_t)(2*kp)*DIM + c], W[(size_t)(2*kp+1)*DIM + c]);
    } else {
      float2 wt = *reinterpret_cast<const float2*>(W + (size_t)c*DIM + 2*kp);
      WTq[ei] = packh(wt.x, wt.y);
    }
  }

  // per-thread pointwise state: ONE element of one batch row
  float x  = x0[(size_t)grow*DIM + pcl];
  float bv = bvec[pcl];

  grid.sync();   // publish Wq/WTq (only full fence in the kernel)

  float t = 0.f, dt = DT0f;
  float k1,k2,k3f,k4,k5,xhi,yreg;
  k1=k2=k3f=k4=k5=xhi=yreg=0.f;

  // 2 rows x 4 cols (stride 128) x 32 kp; depth-4 compute-then-reload pipeline.
  auto mm_store = [&](const unsigned* __restrict__ Wp,
                      const unsigned short (&src)[NROW][DIM]){
    float acc[2][4];
    #pragma unroll
    for (int r = 0; r < 2; ++r)
      #pragma unroll
      for (int j = 0; j < 4; ++j) acc[r][j] = 0.f;
    const unsigned* wp = Wp + (size_t)(ks*8)*2048 + (size_t)cgi*4;
    uint4 wb[4][4];                     // 4 chunks in flight (64 VGPR)
    #pragma unroll
    for (int p = 0; p < 4; ++p)
      #pragma unroll
      for (int j = 0; j < 4; ++j)
        wb[p][j] = *reinterpret_cast<const uint4*>(wp + (size_t)p*2048 + 512*j);
    #pragma unroll
    for (int ch = 0; ch < 8; ++ch){
      const int slot = ch & 3;
      uint4 y0 = *reinterpret_cast<const uint4*>(&src[0][ks*64 + ch*8]);  // broadcast
      uint4 y1 = *reinterpret_cast<const uint4*>(&src[1][ks*64 + ch*8]);
      #pragma unroll
      for (int j = 0; j < 4; ++j){
        uint4 w = wb[slot][j];
        acc[0][j] = dot2f(w.x, y0.x, acc[0][j]);
        acc[0][j] = dot2f(w.y, y0.y, acc[0][j]);
        acc[0][j] = dot2f(w.z, y0.z, acc[0][j]);
        acc[0][j] = dot2f(w.w, y0.w, acc[0][j]);
        acc[1][j] = dot2f(w.x, y1.x, acc[1][j]);
        acc[1][j] = dot2f(w.y, y1.y, acc[1][j]);
        acc[1][j] = dot2f(w.z, y1.z, acc[1][j]);
        acc[1][j] = dot2f(w.w, y1.w, acc[1][j]);
      }
      if (ch + 4 < 8){                  // static (unrolled): reload consumed slot
        #pragma unroll
        for (int j = 0; j < 4; ++j)
          wb[slot][j] = *reinterpret_cast<const uint4*>(wp + (size_t)(ch+4)*2048 + 512*j);
      }
    }
    #pragma unroll
    for (int r = 0; r < 2; ++r)
      #pragma unroll
      for (int j = 0; j < 4; ++j)
        sPart[ks][r][cgi + 128*j] = acc[r][j];
  };

  auto comb = [&](){   // sum the 8 k-slice partials (pointwise layout)
    float g = 0.f;
    #pragma unroll
    for (int kk = 0; kk < 8; ++kk) g += sPart[kk][pr][pcl];
    return g;
  };

  auto set_y = [&](float y){
    yreg = y;
    ylds[pr][pcl] = __half_as_ushort(__float2half(y));
    __syncthreads();
  };
  auto run_fwd = [&](){
    mm_store(Wq, ylds);
    __syncthreads();
    float th = tanhf(comb() + bv);
    slds[pr][pcl] = __half_as_ushort(__float2half(1.f - th*th));
    __syncthreads();
  };
  auto run_bwd = [&](){
    mm_store(WTq, slds);
    __syncthreads();
    return -(2.f*yreg + comb()) * INVD;
  };

  // ---- prologue: k1 = pvf(x0) ----
  set_y(x);
  run_fwd(); k1 = run_bwd();

  for (int iter = 0; iter < 32; ++iter){
    // ---- stages 2..5 ----
    set_y(x + dt*(cA21*k1));
    run_fwd(); k2 = run_bwd();
    set_y(x + dt*(cA31*k1 + cA32*k2));
    run_fwd(); k3f = run_bwd();
    set_y(x + dt*(cA41*k1 + cA42*k2 + cA43*k3f));
    run_fwd(); k4 = run_bwd();
    set_y(x + dt*(cA51*k1 + cA52*k2 + cA53*k3f + cA54*k4));
    run_fwd(); k5 = run_bwd();

    // ---- stage 6 fused: k6 / x_hi / x_lo / err ----
    set_y(x + dt*(cA61*k1 + cA62*k2 + cA63*k3f + cA64*k4 + cA65*k5));
    run_fwd();
    {
      float k6 = run_bwd();
      float hi = x + dt*(cB1*k1 + cB3*k3f + cB4*k4 + cB5*k5 + cB6*k6);
      float lo = x + dt*(cC1*k1 + cC3*k3f + cC4*k4 + cC5*k5);
      xhi = hi;
      float emax = fabsf(hi - lo);
      #pragma unroll
      for (int s = 32; s > 0; s >>= 1) emax = fmaxf(emax, __shfl_xor(emax, s, 64));
      if (lane == 0) red[wid] = emax;
      __syncthreads();
      if (tid == 0){
        float m = red[0];
        #pragma unroll
        for (int wv = 1; wv < 16; ++wv) m = fmaxf(m, red[wv]);
        unsigned old = __hip_atomic_fetch_max(&errs[iter], __float_as_uint(m),
                                              __ATOMIC_RELAXED, __HIP_MEMORY_SCOPE_AGENT);
        if (old != 0xFFFFFFFFu)   // always true; orders arrival after the err RMW
          __hip_atomic_fetch_add(&bar[2*iter], 1u, __ATOMIC_RELAXED, __HIP_MEMORY_SCOPE_AGENT);
      }
    }

    __syncthreads();
    if (tid == 0){
      unsigned v;
      do { __builtin_amdgcn_s_sleep(2);
           v = __hip_atomic_load(&bar[2*iter], __ATOMIC_RELAXED, __HIP_MEMORY_SCOPE_AGENT);
      } while (v < NBLK);
      unsigned eb = __hip_atomic_fetch_max(&errs[iter], 0u,
                                           __ATOMIC_RELAXED, __HIP_MEMORY_SCOPE_AGENT);
      bcast[0] = __uint_as_float(eb);
    }
    __syncthreads();
    const float err = bcast[0];
    const bool accept = (err < TOLf) || (dt <= MIN_DTf);
    if (accept) x = xhi;

    // ---- stop condition: k1_next = pvf(x2); vel from it ----
    set_y(x);
    run_fwd(); k1 = run_bwd();
    {
      float vmax = fabsf(k1);
      #pragma unroll
      for (int s = 32; s > 0; s >>= 1) vmax = fmaxf(vmax, __shfl_xor(vmax, s, 64));
      if (lane == 0) red[wid] = vmax;       // waves 0..7 row 0, 8..15 row 1
      __syncthreads();
      if (tid == 0){
        float r0 = red[0], r1 = red[8];
        #pragma unroll
        for (int wv = 1; wv < 8; ++wv){
          r0 = fmaxf(r0, red[wv]);
          r1 = fmaxf(r1, red[8 + wv]);
        }
        double rsum = (double)r0 + (double)r1;
        unsigned long long fx = (unsigned long long)(rsum * 4294967296.0);
        unsigned long long vo = __hip_atomic_fetch_add(&vels[iter], fx,
                                    __ATOMIC_RELAXED, __HIP_MEMORY_SCOPE_AGENT);
        if (vo != ~0ull)            // always true; orders arrival after the vel RMW
          __hip_atomic_fetch_add(&bar[2*iter+1], 1u, __ATOMIC_RELAXED, __HIP_MEMORY_SCOPE_AGENT);
      }
    }

    __syncthreads();
    if (tid == 0){
      unsigned v;
      do { __builtin_amdgcn_s_sleep(2);
           v = __hip_atomic_load(&bar[2*iter+1], __ATOMIC_RELAXED, __HIP_MEMORY_SCOPE_AGENT);
      } while (v < NBLK);
      unsigned long long sv = __hip_atomic_fetch_add(&vels[iter], 0ull,
                                  __ATOMIC_RELAXED, __HIP_MEMORY_SCOPE_AGENT);
      float vel = (float)((double)sv * (1.0/4294967296.0) / 512.0);
      float t2  = accept ? (t + dt) : t;
      float factor = 0.9f * powf(TOLf / (err + 1e-12f), 0.2f);
      factor = fminf(fmaxf(factor, 0.2f), 2.0f);
      float dtn = fmaxf(dt * factor, MIN_DTf);
      bcast[0] = t2; bcast[1] = dtn;
      bcast[2] = ((t2 > MAXTf) || (vel < VELTOLf)) ? 1.f : 0.f;
    }
    __syncthreads();
    t = bcast[0]; dt = bcast[1];
    if (bcast[2] != 0.f) break;                     // uniform across grid
  }

  out[(size_t)grow*DIM + pcl] = x;
}

extern "C" void kernel_launch(void* const* d_in, const int* in_sizes, int n_in,
                              void* d_out, int out_size, void* d_ws, size_t ws_size,
                              hipStream_t stream)
{
  const float* x0 = (const float*)d_in[0];
  const float* W  = (const float*)d_in[1];
  const float* bv = (const float*)d_in[2];
  float* out = (float*)d_out;
  unsigned char* ws = (unsigned char*)d_ws;

  hipMemsetAsync(ws, 0, 4096, stream);   // barrier slots + errs + vels

  void* args[] = { (void*)&x0, (void*)&W, (void*)&bv, (void*)&out, (void*)&ws };
  (void)in_sizes; (void)n_in; (void)out_size; (void)ws_size;
  hipLaunchCooperativeKernel((void*)hop_kernel, dim3(NBLK), dim3(NTHR), args, 0, stream);
}

// Round 12
// 217.450 us; speedup vs baseline: 1.1651x; 1.1651x over previous
//
#include <hip/hip_runtime.h>
#include <hip/hip_cooperative_groups.h>
#include <hip/hip_fp16.h>
#include <math.h>

namespace cg = cooperative_groups;

#define DIM   512
#define NBLK  256
#define NTHR  1024
#define NROW  2              // rows per block; 256 blocks * 2 = 512

typedef _Float16 h2 __attribute__((ext_vector_type(2)));

#if __has_builtin(__builtin_amdgcn_fdot2)
__device__ __forceinline__ float dot2f(unsigned a, unsigned b, float c){
  return __builtin_amdgcn_fdot2(__builtin_bit_cast(h2, a), __builtin_bit_cast(h2, b), c, false);
}
#else
__device__ __forceinline__ float dot2f(unsigned au, unsigned bu, float c){
  h2 a = __builtin_bit_cast(h2, au), b = __builtin_bit_cast(h2, bu);
  return fmaf((float)a[0], (float)b[0], fmaf((float)a[1], (float)b[1], c));
}
#endif

// ---- RKF56 coefficients ----
constexpr float cA21 = 0.25f;
constexpr float cA31 = (float)(3.0/32.0),     cA32 = (float)(9.0/32.0);
constexpr float cA41 = (float)(1932.0/2197.0),cA42 = (float)(-7200.0/2197.0), cA43 = (float)(7296.0/2197.0);
constexpr float cA51 = (float)(439.0/216.0),  cA52 = -8.0f,                   cA53 = (float)(3680.0/513.0), cA54 = (float)(-845.0/4104.0);
constexpr float cA61 = (float)(-8.0/27.0),    cA62 = 2.0f,                    cA63 = (float)(-3544.0/2565.0), cA64 = (float)(1859.0/4104.0), cA65 = (float)(-11.0/40.0);
constexpr float cB1 = (float)(16.0/135.0), cB3 = (float)(6656.0/12825.0), cB4 = (float)(28561.0/56430.0), cB5 = (float)(-9.0/50.0), cB6 = (float)(2.0/55.0);
constexpr float cC1 = (float)(25.0/216.0), cC3 = (float)(1408.0/2565.0),  cC4 = (float)(2197.0/4104.0),  cC5 = -0.2f;

constexpr float TOLf = 0.01f, MIN_DTf = 0.1f, DT0f = 0.1f, MAXTf = 50.0f, VELTOLf = 0.05f;
constexpr float INVD = 1.0f/512.0f;

__device__ __forceinline__ unsigned packh(float a, float b){
  unsigned short lo = __half_as_ushort(__float2half(a));   // RNE
  unsigned short hi = __half_as_ushort(__float2half(b));
  return (unsigned)lo | ((unsigned)hi << 16);
}

__global__ void __launch_bounds__(NTHR, 4)
hop_kernel(const float* __restrict__ x0, const float* __restrict__ W,
           const float* __restrict__ bvec, float* __restrict__ out,
           unsigned char* __restrict__ ws)
{
  cg::grid_group grid = cg::this_grid();

  unsigned*           bar  = (unsigned*)ws;                    // 64 slots
  unsigned*           errs = (unsigned*)(ws + 384);            // errs[32]
  unsigned long long* vels = (unsigned long long*)(ws + 512);  // vels[32]
  unsigned*           Wq   = (unsigned*)(ws + 4096);           // [kp/4][c][kp&3] f16x2, 512 KB
  unsigned*           WTq  = Wq + 131072;                      // transposed, 512 KB

  const int tid  = threadIdx.x;
  const int b    = blockIdx.x;
  const int wid  = tid >> 6;           // wave 0..15
  const int lane = tid & 63;

  // matmul coords: 4 k-slices x 256 col-groups; thread owns cols {cgi, cgi+256}
  const int ks  = tid >> 8;            // 0..3  (kp range [ks*64, ks*64+64))
  const int cgi = tid & 255;           // 0..255
  // pointwise coords: one row, ONE column
  const int pr   = tid >> 9;           // 0..1
  const int pcl  = tid & 511;          // col 0..511
  const int grow = b*NROW + pr;        // global batch row

  __shared__ __align__(16) unsigned short ylds[NROW][DIM];   // f16 y, 2 KB
  __shared__ __align__(16) unsigned short slds[NROW][DIM];   // f16 sech2, 2 KB
  __shared__ __align__(16) float sPart[4][NROW][DIM];        // k-slice partials, 16 KB
  __shared__ float red[16];
  __shared__ float bcast[4];

  // ---- one-time: W -> interleaved packed f16 (normal + transposed) ----
  {
    int e = b*NTHR + tid;               // [0, 262144): half pack Wq, half WTq
    int ei = e & 131071;
    int kpq = ei >> 11, rem = ei & 2047;
    int c = rem >> 2, k3 = rem & 3;
    int kp = kpq*4 + k3;
    if (e < 131072){
      Wq[ei] = packh(W[(size_t)(2*kp)*DIM + c], W[(size_t)(2*kp+1)*DIM + c]);
    } else {
      float2 wt = *reinterpret_cast<const float2*>(W + (size_t)c*DIM + 2*kp);
      WTq[ei] = packh(wt.x, wt.y);
    }
  }

  // per-thread pointwise state: ONE element of one batch row
  float x  = x0[(size_t)grow*DIM + pcl];
  float bv = bvec[pcl];

  grid.sync();   // publish Wq/WTq (only full fence in the kernel)

  float t = 0.f, dt = DT0f;
  float k1,k2,k3f,k4,k5,xhi,yreg;
  k1=k2=k3f=k4=k5=xhi=yreg=0.f;

  // 2 rows x 2 cols (stride 256) x 64 kp; depth-2 reload pipeline (fits 64 VGPR).
  auto mm_store = [&](const unsigned* __restrict__ Wp,
                      const unsigned short (&src)[NROW][DIM]){
    float a00=0.f, a01=0.f, a10=0.f, a11=0.f;
    const unsigned* wp = Wp + (size_t)(ks*16)*2048 + (size_t)cgi*4;
    // depth-2 slots, 2 cols each (16 VGPR of W in flight)
    uint4 s0c0 = *reinterpret_cast<const uint4*>(wp);
    uint4 s0c1 = *reinterpret_cast<const uint4*>(wp + 1024);
    uint4 s1c0 = *reinterpret_cast<const uint4*>(wp + 2048);
    uint4 s1c1 = *reinterpret_cast<const uint4*>(wp + 2048 + 1024);
    #pragma unroll
    for (int ch = 0; ch < 16; ++ch){
      uint4 y0 = *reinterpret_cast<const uint4*>(&src[0][ks*128 + ch*8]);  // broadcast
      uint4 y1 = *reinterpret_cast<const uint4*>(&src[1][ks*128 + ch*8]);
      uint4 w0, w1;
      if ((ch & 1) == 0){ w0 = s0c0; w1 = s0c1; }
      else              { w0 = s1c0; w1 = s1c1; }
      if (ch + 2 < 16){                 // static (unrolled) reload of consumed slot
        const unsigned* np = wp + (size_t)(ch+2)*2048;
        if ((ch & 1) == 0){
          s0c0 = *reinterpret_cast<const uint4*>(np);
          s0c1 = *reinterpret_cast<const uint4*>(np + 1024);
        } else {
          s1c0 = *reinterpret_cast<const uint4*>(np);
          s1c1 = *reinterpret_cast<const uint4*>(np + 1024);
        }
      }
      a00 = dot2f(w0.x, y0.x, a00); a00 = dot2f(w0.y, y0.y, a00);
      a00 = dot2f(w0.z, y0.z, a00); a00 = dot2f(w0.w, y0.w, a00);
      a01 = dot2f(w1.x, y0.x, a01); a01 = dot2f(w1.y, y0.y, a01);
      a01 = dot2f(w1.z, y0.z, a01); a01 = dot2f(w1.w, y0.w, a01);
      a10 = dot2f(w0.x, y1.x, a10); a10 = dot2f(w0.y, y1.y, a10);
      a10 = dot2f(w0.z, y1.z, a10); a10 = dot2f(w0.w, y1.w, a10);
      a11 = dot2f(w1.x, y1.x, a11); a11 = dot2f(w1.y, y1.y, a11);
      a11 = dot2f(w1.z, y1.z, a11); a11 = dot2f(w1.w, y1.w, a11);
    }
    sPart[ks][0][cgi]       = a00;
    sPart[ks][0][cgi + 256] = a01;
    sPart[ks][1][cgi]       = a10;
    sPart[ks][1][cgi + 256] = a11;
  };

  auto comb = [&](){   // sum the 4 k-slice partials (pointwise layout)
    float g = 0.f;
    #pragma unroll
    for (int kk = 0; kk < 4; ++kk) g += sPart[kk][pr][pcl];
    return g;
  };

  auto set_y = [&](float y){
    yreg = y;
    ylds[pr][pcl] = __half_as_ushort(__float2half(y));
    __syncthreads();
  };
  auto run_fwd = [&](){
    mm_store(Wq, ylds);
    __syncthreads();
    float th = tanhf(comb() + bv);
    slds[pr][pcl] = __half_as_ushort(__float2half(1.f - th*th));
    __syncthreads();
  };
  auto run_bwd = [&](){
    mm_store(WTq, slds);
    __syncthreads();
    return -(2.f*yreg + comb()) * INVD;
  };

  // ---- prologue: k1 = pvf(x0) ----
  set_y(x);
  run_fwd(); k1 = run_bwd();

  for (int iter = 0; iter < 32; ++iter){
    // ---- stages 2..5 ----
    set_y(x + dt*(cA21*k1));
    run_fwd(); k2 = run_bwd();
    set_y(x + dt*(cA31*k1 + cA32*k2));
    run_fwd(); k3f = run_bwd();
    set_y(x + dt*(cA41*k1 + cA42*k2 + cA43*k3f));
    run_fwd(); k4 = run_bwd();
    set_y(x + dt*(cA51*k1 + cA52*k2 + cA53*k3f + cA54*k4));
    run_fwd(); k5 = run_bwd();

    // ---- stage 6 fused: k6 / x_hi / x_lo / err ----
    set_y(x + dt*(cA61*k1 + cA62*k2 + cA63*k3f + cA64*k4 + cA65*k5));
    run_fwd();
    {
      float k6 = run_bwd();
      float hi = x + dt*(cB1*k1 + cB3*k3f + cB4*k4 + cB5*k5 + cB6*k6);
      float lo = x + dt*(cC1*k1 + cC3*k3f + cC4*k4 + cC5*k5);
      xhi = hi;
      float emax = fabsf(hi - lo);
      #pragma unroll
      for (int s = 32; s > 0; s >>= 1) emax = fmaxf(emax, __shfl_xor(emax, s, 64));
      if (lane == 0) red[wid] = emax;
      __syncthreads();
      if (tid == 0){
        float m = red[0];
        #pragma unroll
        for (int wv = 1; wv < 16; ++wv) m = fmaxf(m, red[wv]);
        unsigned old = __hip_atomic_fetch_max(&errs[iter], __float_as_uint(m),
                                              __ATOMIC_RELAXED, __HIP_MEMORY_SCOPE_AGENT);
        if (old != 0xFFFFFFFFu)   // always true; orders arrival after the err RMW
          __hip_atomic_fetch_add(&bar[2*iter], 1u, __ATOMIC_RELAXED, __HIP_MEMORY_SCOPE_AGENT);
      }
    }

    __syncthreads();
    if (tid == 0){
      unsigned v;
      do { __builtin_amdgcn_s_sleep(2);
           v = __hip_atomic_load(&bar[2*iter], __ATOMIC_RELAXED, __HIP_MEMORY_SCOPE_AGENT);
      } while (v < NBLK);
      unsigned eb = __hip_atomic_fetch_max(&errs[iter], 0u,
                                           __ATOMIC_RELAXED, __HIP_MEMORY_SCOPE_AGENT);
      bcast[0] = __uint_as_float(eb);
    }
    __syncthreads();
    const float err = bcast[0];
    const bool accept = (err < TOLf) || (dt <= MIN_DTf);
    if (accept) x = xhi;

    // ---- stop condition: k1_next = pvf(x2); vel from it ----
    set_y(x);
    run_fwd(); k1 = run_bwd();
    {
      float vmax = fabsf(k1);
      #pragma unroll
      for (int s = 32; s > 0; s >>= 1) vmax = fmaxf(vmax, __shfl_xor(vmax, s, 64));
      if (lane == 0) red[wid] = vmax;       // waves 0..7 row 0, 8..15 row 1
      __syncthreads();
      if (tid == 0){
        float r0 = red[0], r1 = red[8];
        #pragma unroll
        for (int wv = 1; wv < 8; ++wv){
          r0 = fmaxf(r0, red[wv]);
          r1 = fmaxf(r1, red[8 + wv]);
        }
        double rsum = (double)r0 + (double)r1;
        unsigned long long fx = (unsigned long long)(rsum * 4294967296.0);
        unsigned long long vo = __hip_atomic_fetch_add(&vels[iter], fx,
                                    __ATOMIC_RELAXED, __HIP_MEMORY_SCOPE_AGENT);
        if (vo != ~0ull)            // always true; orders arrival after the vel RMW
          __hip_atomic_fetch_add(&bar[2*iter+1], 1u, __ATOMIC_RELAXED, __HIP_MEMORY_SCOPE_AGENT);
      }
    }

    __syncthreads();
    if (tid == 0){
      unsigned v;
      do { __builtin_amdgcn_s_sleep(2);
           v = __hip_atomic_load(&bar[2*iter+1], __ATOMIC_RELAXED, __HIP_MEMORY_SCOPE_AGENT);
      } while (v < NBLK);
      unsigned long long sv = __hip_atomic_fetch_add(&vels[iter], 0ull,
                                  __ATOMIC_RELAXED, __HIP_MEMORY_SCOPE_AGENT);
      float vel = (float)((double)sv * (1.0/4294967296.0) / 512.0);
      float t2  = accept ? (t + dt) : t;
      float factor = 0.9f * powf(TOLf / (err + 1e-12f), 0.2f);
      factor = fminf(fmaxf(factor, 0.2f), 2.0f);
      float dtn = fmaxf(dt * factor, MIN_DTf);
      bcast[0] = t2; bcast[1] = dtn;
      bcast[2] = ((t2 > MAXTf) || (vel < VELTOLf)) ? 1.f : 0.f;
    }
    __syncthreads();
    t = bcast[0]; dt = bcast[1];
    if (bcast[2] != 0.f) break;                     // uniform across grid
  }

  out[(size_t)grow*DIM + pcl] = x;
}

extern "C" void kernel_launch(void* const* d_in, const int* in_sizes, int n_in,
                              void* d_out, int out_size, void* d_ws, size_t ws_size,
                              hipStream_t stream)
{
  const float* x0 = (const float*)d_in[0];
  const float* W  = (const float*)d_in[1];
  const float* bv = (const float*)d_in[2];
  float* out = (float*)d_out;
  unsigned char* ws = (unsigned char*)d_ws;

  hipMemsetAsync(ws, 0, 4096, stream);   // barrier slots + errs + vels

  void* args[] = { (void*)&x0, (void*)&W, (void*)&bv, (void*)&out, (void*)&ws };
  (void)in_sizes; (void)n_in; (void)out_size; (void)ws_size;
  hipLaunchCooperativeKernel((void*)hop_kernel, dim3(NBLK), dim3(NTHR), args, 0, stream);
}